// Round 12
// baseline (196.516 us; speedup 1.0000x reference)
//
#include <hip/hip_runtime.h>
#include <hip/hip_bf16.h>
#include <stdint.h>

typedef __bf16 bf16_t;
typedef bf16_t bf16x8 __attribute__((ext_vector_type(8)));
typedef float f32x4 __attribute__((ext_vector_type(4)));
typedef int int4v __attribute__((ext_vector_type(4)));

#define T_LEN 2048
#define C_LEN 2048
#define NB 128
#define TN 256
#define SROWS 2064    // 16 zero-halo rows + 2048 data rows per batch
#define XROWS 288     // 9 x 4KB GLL rounds (256 thr); rows 0..271 consumed

// async global->LDS, 16B per lane; LDS dest = wave-uniform base + lane*16
#define GLL(gp, lp) __builtin_amdgcn_global_load_lds( \
    (const __attribute__((address_space(1))) uint32_t*)(gp), \
    (__attribute__((address_space(3))) uint32_t*)(lp), 16, 0, 0)

// DPP lane moves within 16-lane rows (row_shr:1 == lane i <- i-1, per AMD
// cross-lane docs / prefix-sum idiom; row_shl:N == lane i <- i+N).
#define DPP_SHL1(x) __builtin_amdgcn_update_dpp(0, (x), 0x101, 0xF, 0xF, true)
#define DPP_SHR(x, CTRL) __builtin_amdgcn_update_dpp(0, (x), (CTRL), 0xF, 0xF, true)

// ---------------------------------------------------------------------------
// Prepack weights into per-lane MFMA A-fragment layout (verified r1-r11):
// wpk[blk][s(32)][mt(4)][lane(64)][j(8)]
//   = bv[blk][o = mt*16 + (lane&15)][i = (s&1)*32 + (lane>>4)*8 + j][k = s>>1]
// ---------------------------------------------------------------------------
__global__ __launch_bounds__(256) void prepack_kernel(
    const float* __restrict__ bv, bf16_t* __restrict__ wpk)
{
  const int blk = blockIdx.x;
  const int mt  = blockIdx.y;
  const int tid = threadIdx.x;
  __shared__ float lw[16 * 64 * 17];

  const float* src = bv + (size_t)blk * 65536 + (size_t)mt * 16384;
  for (int p = 0; p < 16; ++p) {
    int idx = p * 1024 + tid * 4;
    const float4 v = *(const float4*)(src + idx);
    int o = idx >> 10;
    int i = (idx >> 4) & 63;
    int k = idx & 15;
    float* d = &lw[(o * 64 + i) * 17 + k];
    d[0] = v.x; d[1] = v.y; d[2] = v.z; d[3] = v.w;
  }
  __syncthreads();

  const int e0 = tid * 2;
  const int l  = e0 >> 3;
  const int j  = e0 & 7;
  const int o  = l & 15;
  for (int ks = 0; ks < 32; ++ks) {
    const int k  = ks >> 1;
    const int i0 = (ks & 1) * 32 + (l >> 4) * 8 + j;
    const float a = lw[(o * 64 + i0) * 17 + k];
    const float b = lw[(o * 64 + i0 + 1) * 17 + k];
    const uint16_t ba = __builtin_bit_cast(uint16_t, (bf16_t)a);
    const uint16_t bb = __builtin_bit_cast(uint16_t, (bf16_t)b);
    const uint32_t packed = (uint32_t)ba | ((uint32_t)bb << 16);
    const size_t off = ((((size_t)blk * 32 + ks) * 4 + mt) * 512) + e0;
    *(uint32_t*)(wpk + off) = packed;
  }
}

// ---------------------------------------------------------------------------
// Zero the halo rows of S.
// ---------------------------------------------------------------------------
__global__ __launch_bounds__(256) void padzero_kernel(bf16_t* __restrict__ S)
{
  const int p = blockIdx.x;  // 0..79
  const size_t g = (p < 64) ? ((size_t)(p >> 4) * SROWS + (p & 15))
                            : ((size_t)4 * SROWS + (p - 64));
  uint4 z = {0u, 0u, 0u, 0u};
  *(uint4*)(S + g * C_LEN + (size_t)threadIdx.x * 8) = z;
}

// ---------------------------------------------------------------------------
// x prepass: f32 [n][c][t] -> bf16 S[n][16+t][c'], c' = c ^ ((t&7)<<3)
// within each 64-ch block (XOR swizzle baked into global layout).
// ---------------------------------------------------------------------------
__global__ __launch_bounds__(256) void xprep_kernel(
    const float* __restrict__ x, bf16_t* __restrict__ S)
{
  const int tb = blockIdx.x, cb = blockIdx.y, n = blockIdx.z;
  const int tid = threadIdx.x;
  __shared__ float lt[64 * 67 + 4];

  #pragma unroll
  for (int p = 0; p < 4; ++p) {
    const int idx = p * 256 + tid;
    const int c   = idx >> 4;
    const int t4  = (idx & 15) * 4;
    const float4 v = *(const float4*)(
        x + ((size_t)n * C_LEN + cb * 64 + c) * T_LEN + tb * 64 + t4);
    float* d = &lt[c * 67 + t4];
    d[0] = v.x; d[1] = v.y; d[2] = v.z; d[3] = v.w;
  }
  __syncthreads();

  #pragma unroll
  for (int p = 0; p < 2; ++p) {
    const int idx = p * 256 + tid;
    const int tl  = idx >> 3;
    const int seg = idx & 7;
    const int t   = tb * 64 + tl;
    const int cbase = (seg * 8) ^ ((t & 7) << 3);
    uint32_t w[4];
    #pragma unroll
    for (int h = 0; h < 4; ++h) {
      const float a = lt[(cbase + 2 * h) * 67 + tl];
      const float b = lt[(cbase + 2 * h + 1) * 67 + tl];
      const uint16_t ba = __builtin_bit_cast(uint16_t, (bf16_t)a);
      const uint16_t bb = __builtin_bit_cast(uint16_t, (bf16_t)b);
      w[h] = (uint32_t)ba | ((uint32_t)bb << 16);
    }
    uint4 u4 = {w[0], w[1], w[2], w[3]};
    *(uint4*)(S + ((size_t)n * SROWS + 16 + t) * C_LEN + cb * 64 + seg * 8) = u4;
  }
}

// ---------------------------------------------------------------------------
// Main kernel: 256 thr (4 waves), ~77.4 KB LDS -> 2 WG/CU.
// Conv-structure B-reuse: the B-fragment for tap k+1 equals tap k's shifted
// one row along l15 (frag value is swizzle-independent). Per phase:
//   bq[kk][nt] <- row_shl:1(bq[kk][nt]); lane15 patched from a single b128
//   "entering rows" read (lanes l15=12..15 fetch rows nt=0..3) extracted
//   via row_shr:(3-nt) + cndmask.  B LDS reads: 128 -> 8 init + 32 patch
//   per block per wave; per-CU LDS (~960 cyc/window) drops below the MFMA
//   floor (1241) for the first time.
// A: r11's ring-5 x 8KB GLL + ping-pong regs + tail-vmcnt ledger (proven):
//   tail of c: queue [W(c+2..c+4)]=6 -> vmcnt(4) forces W(c+2) cross-wave.
//   Seam: x:9 + W0..3:8 -> vmcnt(4) (x,W0,W1 forced).  Tails: c<=11:4,
//   c=12:2, c=13:0.  Phase 15 issues no xst reads -> seam x-overwrite safe.
// ---------------------------------------------------------------------------
__global__ __launch_bounds__(256, 2) void bsconv_kernel(
    const bf16_t* __restrict__ S, const bf16_t* __restrict__ wpk,
    const int* __restrict__ cols, const int* __restrict__ rows,
    float* __restrict__ y)
{
  const int tt = blockIdx.x, tr = blockIdx.y, n = blockIdx.z;
  const int t0 = tt * TN;
  const int tid = threadIdx.x;
  const int lane = tid & 63, wv = tid >> 6;   // wv 0..3
  const int l15 = lane & 15, lg = lane >> 4;
  const bool is15 = (l15 == 15);

  __shared__ __attribute__((aligned(16))) bf16_t xst[XROWS * 64];   // 36864 B
  __shared__ __attribute__((aligned(16))) bf16_t wring[5][4096];    // 40960 B
  __shared__ int alist[NB];                   // packed: blk | (col<<8)
  __shared__ unsigned long long wmask[2];

  // ---- build active-block list (order-preserving => deterministic) ----
  {
    const int r  = (tid < NB) ? rows[tid] : -1;
    const int cb = (tid < NB) ? cols[tid] : 0;
    const bool match = (r == tr);
    const unsigned long long m = __ballot(match);
    if (wv < 2 && lane == 0) wmask[wv] = m;
    __syncthreads();
    if (match) {
      int pos = __popcll(wmask[wv] & ((1ull << lane) - 1ull));
      if (wv == 1) pos += __popcll(wmask[0]);
      alist[pos] = tid | (cb << 8);
    }
    __syncthreads();
  }
  const int cnt = __popcll(wmask[0]) + __popcll(wmask[1]);

  f32x4 acc[4][4];
  #pragma unroll
  for (int a = 0; a < 4; ++a)
    #pragma unroll
    for (int b = 0; b < 4; ++b) {
      f32x4 z = {0.f, 0.f, 0.f, 0.f};
      acc[a][b] = z;
    }

  const size_t srow0 = (size_t)n * SROWS + t0;  // S row of LDS row u=0
  const int lxb = tid * 16;                     // lane byte within a 4KB round

  auto issue_x = [&](int cb) {                  // 9 rounds = 36 KB, single buf
    #pragma unroll
    for (int q = 0; q < 9; ++q) {
      const int lb = q * 4096 + lxb;
      const int u  = lb >> 7;                   // LDS row (128 B rows)
      const int ib = (lb >> 1) & 63;
      GLL(S + (srow0 + u) * C_LEN + cb * 64 + ib, (char*)xst + lb);
    }
  };
  auto issue_wc = [&](const bf16_t* wblk, int c, int slot) {  // 8KB chunk
    const bf16_t* wsrc = wblk + (size_t)c * 4096;
    #pragma unroll
    for (int p = 0; p < 2; ++p) {
      const int lb = p * 4096 + lxb;
      GLL(wsrc + (lb >> 1), (char*)wring[slot] + lb);
    }
  };

  int4v bq[2][4];          // B fragments, live across the block (kk, nt)
  int4v pq[2];             // patch register (entering rows), per kk
  bf16x8 afA[2][4], afB[2][4];   // A ping-pong (kk, mt)

  auto read_A = [&](int c, bf16x8 (&aD)[2][4]) {
    const bf16_t* wl = wring[c % 5];
    #pragma unroll
    for (int kk = 0; kk < 2; ++kk)
      #pragma unroll
      for (int mt = 0; mt < 4; ++mt)
        aD[kk][mt] = *(const bf16x8*)(wl + ((kk * 4 + mt) * 64 + lane) * 8);
  };
  auto read_binit = [&]() {                    // frag(0): rows wv*64+1..+65
    #pragma unroll
    for (int kk = 0; kk < 2; ++kk)
      #pragma unroll
      for (int nt = 0; nt < 4; ++nt) {
        const int ub   = wv * 64 + l15 + 1 + nt * 16;
        const int scol = (kk * 32 + lg * 8) ^ ((ub & 7) << 3);
        bq[kk][nt] = *(const int4v*)(xst + ub * 64 + scol);
      }
  };
  auto read_patch = [&](int c) {   // entering rows for tap c+1 (l15<12: bcast)
    const int pl   = (l15 < 12) ? 0 : (l15 - 12);         // nt index
    const int prow = wv * 64 + c + 17 + pl * 16;          // <= 271 < XROWS
    #pragma unroll
    for (int kk = 0; kk < 2; ++kk) {
      const int scol = (kk * 32 + lg * 8) ^ ((prow & 7) << 3);
      pq[kk] = *(const int4v*)(xst + prow * 64 + scol);
    }
  };

// advance B register (KK,NT) to the next tap; CTRL = row_shr:(3-NT) encoding
#define BADV(KK, NT, CTRL) do {                                           \
    _Pragma("unroll")                                                     \
    for (int d = 0; d < 4; ++d) {                                         \
      const int sh = DPP_SHL1(bq[KK][NT][d]);                             \
      const int pe = DPP_SHR(pq[KK][d], CTRL);                            \
      bq[KK][NT][d] = is15 ? pe : sh;                                     \
    } } while (0)
#define BADV3(KK) do {                                                    \
    _Pragma("unroll")                                                     \
    for (int d = 0; d < 4; ++d) {                                         \
      const int sh = DPP_SHL1(bq[KK][3][d]);                              \
      bq[KK][3][d] = is15 ? pq[KK][d] : sh;                               \
    } } while (0)

  for (int j = 0; j < cnt; ++j) {
    const int aj = alist[j];
    const bf16_t* wblk = wpk + (size_t)(aj & 255) * 65536;
    const int cb = aj >> 8;

    // ---- seam: stage x + W chunks 0..3 into ring slots 0..3 ----
    issue_x(cb);
    issue_wc(wblk, 0, 0);
    issue_wc(wblk, 1, 1);
    issue_wc(wblk, 2, 2);
    issue_wc(wblk, 3, 3);
    asm volatile("s_waitcnt vmcnt(4)" ::: "memory");  // x,W0,W1 forced landed
    __builtin_amdgcn_s_barrier();                     // all waves: x,W0,W1 ok
    read_A(0, afA);
    read_binit();

    #pragma unroll
    for (int c = 0; c < 16; ++c) {
      asm volatile("s_waitcnt lgkmcnt(0)" ::: "memory");  // frags(c) in regs
      __builtin_amdgcn_sched_barrier(0);                  // rule 18 fence
      if (c <= 11) issue_wc(wblk, c + 4, (c + 4) % 5);    // head GLL issue
      if (c < 15) read_patch(c);      // latency hidden under MFMA cluster

      __builtin_amdgcn_s_setprio(1);
      #pragma unroll
      for (int kk = 0; kk < 2; ++kk)
        #pragma unroll
        for (int nt = 0; nt < 4; ++nt) {
          const bf16x8 bfr = __builtin_bit_cast(bf16x8, bq[kk][nt]);
          #pragma unroll
          for (int mt = 0; mt < 4; ++mt)
            acc[mt][nt] = __builtin_amdgcn_mfma_f32_16x16x32_bf16(
                ((c & 1) == 0) ? afA[kk][mt] : afB[kk][mt],
                bfr, acc[mt][nt], 0, 0, 0);
        }
      __builtin_amdgcn_s_setprio(0);

      if (c < 15) {
        if ((c & 1) == 0) read_A(c + 1, afB);
        else              read_A(c + 1, afA);
        // B advance to tap c+1 (shift + patch; bit-identical to re-read)
        BADV(0, 0, 0x113); BADV(0, 1, 0x112); BADV(0, 2, 0x111); BADV3(0);
        BADV(1, 0, 0x113); BADV(1, 1, 0x112); BADV(1, 2, 0x111); BADV3(1);
      }
      __builtin_amdgcn_sched_barrier(0);
      // ---- counted TAIL wait (r11-proven): forces W(c+2) cross-wave ----
      if (c <= 11)      asm volatile("s_waitcnt vmcnt(4)" ::: "memory");
      else if (c == 12) asm volatile("s_waitcnt vmcnt(2)" ::: "memory");
      else if (c == 13) asm volatile("s_waitcnt vmcnt(0)" ::: "memory");
      __builtin_amdgcn_s_barrier();
    }
  }

  // ---- store (each output element exactly once; empty rows store zeros) ----
  const int mlo = ((lane >> 4) & 3) * 4, nn = lane & 15;
  #pragma unroll
  for (int mt = 0; mt < 4; ++mt) {
    #pragma unroll
    for (int nt = 0; nt < 4; ++nt) {
      const int t = t0 + wv * 64 + nt * 16 + nn;
      float* yp = y + ((size_t)n * C_LEN + (size_t)(tr * 64 + mt * 16 + mlo)) * T_LEN + t;
      #pragma unroll
      for (int r = 0; r < 4; ++r)
        yp[(size_t)r * T_LEN] = acc[mt][nt][r];
    }
  }
}

extern "C" void kernel_launch(void* const* d_in, const int* in_sizes, int n_in,
                              void* d_out, int out_size, void* d_ws, size_t ws_size,
                              hipStream_t stream) {
  const float* x   = (const float*)d_in[0];
  const float* bv  = (const float*)d_in[1];
  const int* cols  = (const int*)d_in[2];
  const int* rows  = (const int*)d_in[3];
  float* y = (float*)d_out;

  // ws layout: [wpk: 16,777,216 B][S: 33,882,112 B]  (needs ws >= 50.7 MB)
  bf16_t* wpk = (bf16_t*)d_ws;
  bf16_t* S   = (bf16_t*)((char*)d_ws + 16777216);

  prepack_kernel<<<dim3(128, 4), dim3(256), 0, stream>>>(bv, wpk);
  padzero_kernel<<<dim3(80), dim3(256), 0, stream>>>(S);
  xprep_kernel<<<dim3(32, 32, 4), dim3(256), 0, stream>>>(x, S);
  bsconv_kernel<<<dim3(8, 32, 4), dim3(256), 0, stream>>>(S, wpk, cols, rows, y);
}

// Round 13
// 185.572 us; speedup vs baseline: 1.0590x; 1.0590x over previous
//
#include <hip/hip_runtime.h>
#include <hip/hip_bf16.h>
#include <stdint.h>

typedef __bf16 bf16_t;
typedef bf16_t bf16x8 __attribute__((ext_vector_type(8)));
typedef float f32x4 __attribute__((ext_vector_type(4)));

#define T_LEN 2048
#define C_LEN 2048
#define NB 128
#define TN 256
#define SROWS 2064    // 16 zero-halo rows + 2048 data rows per batch
#define XROWS 288     // 9 x 4KB GLL rounds (256 thr); rows 0..271 consumed

// async global->LDS, 16B per lane; LDS dest = wave-uniform base + lane*16
#define GLL(gp, lp) __builtin_amdgcn_global_load_lds( \
    (const __attribute__((address_space(1))) uint32_t*)(gp), \
    (__attribute__((address_space(3))) uint32_t*)(lp), 16, 0, 0)

// ---------------------------------------------------------------------------
// Prepack weights into per-lane MFMA A-fragment layout (verified r1-r12):
// wpk[blk][ks(32)][mt(4)][lane(64)][j(8)]
//   = bv[blk][o = mt*16 + (lane&15)][i = (ks&1)*32 + (lane>>4)*8 + j][k = ks>>1]
// ---------------------------------------------------------------------------
__global__ __launch_bounds__(256) void prepack_kernel(
    const float* __restrict__ bv, bf16_t* __restrict__ wpk)
{
  const int blk = blockIdx.x;
  const int mt  = blockIdx.y;
  const int tid = threadIdx.x;
  __shared__ float lw[16 * 64 * 17];

  const float* src = bv + (size_t)blk * 65536 + (size_t)mt * 16384;
  for (int p = 0; p < 16; ++p) {
    int idx = p * 1024 + tid * 4;
    const float4 v = *(const float4*)(src + idx);
    int o = idx >> 10;
    int i = (idx >> 4) & 63;
    int k = idx & 15;
    float* d = &lw[(o * 64 + i) * 17 + k];
    d[0] = v.x; d[1] = v.y; d[2] = v.z; d[3] = v.w;
  }
  __syncthreads();

  const int e0 = tid * 2;
  const int l  = e0 >> 3;
  const int j  = e0 & 7;
  const int o  = l & 15;
  for (int ks = 0; ks < 32; ++ks) {
    const int k  = ks >> 1;
    const int i0 = (ks & 1) * 32 + (l >> 4) * 8 + j;
    const float a = lw[(o * 64 + i0) * 17 + k];
    const float b = lw[(o * 64 + i0 + 1) * 17 + k];
    const uint16_t ba = __builtin_bit_cast(uint16_t, (bf16_t)a);
    const uint16_t bb = __builtin_bit_cast(uint16_t, (bf16_t)b);
    const uint32_t packed = (uint32_t)ba | ((uint32_t)bb << 16);
    const size_t off = ((((size_t)blk * 32 + ks) * 4 + mt) * 512) + e0;
    *(uint32_t*)(wpk + off) = packed;
  }
}

// ---------------------------------------------------------------------------
// Zero the halo rows of S.
// ---------------------------------------------------------------------------
__global__ __launch_bounds__(256) void padzero_kernel(bf16_t* __restrict__ S)
{
  const int p = blockIdx.x;  // 0..79
  const size_t g = (p < 64) ? ((size_t)(p >> 4) * SROWS + (p & 15))
                            : ((size_t)4 * SROWS + (p - 64));
  uint4 z = {0u, 0u, 0u, 0u};
  *(uint4*)(S + g * C_LEN + (size_t)threadIdx.x * 8) = z;
}

// ---------------------------------------------------------------------------
// x prepass: f32 [n][c][t] -> bf16 S[n][16+t][c'], c' = c ^ ((t&7)<<3)
// within each 64-ch block (XOR swizzle baked into global layout).
// ---------------------------------------------------------------------------
__global__ __launch_bounds__(256) void xprep_kernel(
    const float* __restrict__ x, bf16_t* __restrict__ S)
{
  const int tb = blockIdx.x, cb = blockIdx.y, n = blockIdx.z;
  const int tid = threadIdx.x;
  __shared__ float lt[64 * 67 + 4];

  #pragma unroll
  for (int p = 0; p < 4; ++p) {
    const int idx = p * 256 + tid;
    const int c   = idx >> 4;
    const int t4  = (idx & 15) * 4;
    const float4 v = *(const float4*)(
        x + ((size_t)n * C_LEN + cb * 64 + c) * T_LEN + tb * 64 + t4);
    float* d = &lt[c * 67 + t4];
    d[0] = v.x; d[1] = v.y; d[2] = v.z; d[3] = v.w;
  }
  __syncthreads();

  #pragma unroll
  for (int p = 0; p < 2; ++p) {
    const int idx = p * 256 + tid;
    const int tl  = idx >> 3;
    const int seg = idx & 7;
    const int t   = tb * 64 + tl;
    const int cbase = (seg * 8) ^ ((t & 7) << 3);
    uint32_t w[4];
    #pragma unroll
    for (int h = 0; h < 4; ++h) {
      const float a = lt[(cbase + 2 * h) * 67 + tl];
      const float b = lt[(cbase + 2 * h + 1) * 67 + tl];
      const uint16_t ba = __builtin_bit_cast(uint16_t, (bf16_t)a);
      const uint16_t bb = __builtin_bit_cast(uint16_t, (bf16_t)b);
      w[h] = (uint32_t)ba | ((uint32_t)bb << 16);
    }
    uint4 u4 = {w[0], w[1], w[2], w[3]};
    *(uint4*)(S + ((size_t)n * SROWS + 16 + t) * C_LEN + cb * 64 + seg * 8) = u4;
  }
}

// ---------------------------------------------------------------------------
// Main kernel: 256 thr (4 waves), ~53.8 KB LDS -> 3 WG/CU (12 waves/CU).
// Structure = r6 (proven 2-barrier phase loop, tail x-issue), W chunks
// shrunk to 2 x 8KB (2 ks/chunk, 16 phases/block) to fit 3 WGs per CU:
// three independent barrier groups de-lockstep the LDS and matrix pipes
// (the measured failure mode of the 2-WG variants was lockstep phase
// alternation: LDS 82us + MFMA 66us summed instead of overlapped).
// Counted vmcnt ledger (GLL-only, uniform, FIFO; r6 positions):
//  block entry: [W0:2, x:9] (x issued at prev block tail; first block at
//  prologue).  c<15: issue W(c+1):2 -> wait vmcnt(2) (x + W(c) landed).
//  c=15: issue next block W0 into buf0 (last read c=14, drained a barrier
//  ago) -> wait vmcnt(2); last block: vmcnt(0).  After trailing barrier of
//  c=15: issue x(j+1):9 (all xst reads lgkm-drained; r6-proven safe).
// ---------------------------------------------------------------------------
__global__ __launch_bounds__(256, 2) void bsconv_kernel(
    const bf16_t* __restrict__ S, const bf16_t* __restrict__ wpk,
    const int* __restrict__ cols, const int* __restrict__ rows,
    float* __restrict__ y)
{
  const int tt = blockIdx.x, tr = blockIdx.y, n = blockIdx.z;
  const int t0 = tt * TN;
  const int tid = threadIdx.x;
  const int lane = tid & 63, wv = tid >> 6;   // wv 0..3

  __shared__ __attribute__((aligned(16))) bf16_t xst[XROWS * 64];  // 36864 B
  __shared__ __attribute__((aligned(16))) bf16_t wlds[2][4096];    // 16384 B
  __shared__ int alist[NB];                   // packed: blk | (col<<8)
  __shared__ unsigned long long wmask[2];

  // ---- build active-block list (order-preserving => deterministic) ----
  {
    const int r  = (tid < NB) ? rows[tid] : -1;
    const int cb = (tid < NB) ? cols[tid] : 0;
    const bool match = (r == tr);
    const unsigned long long m = __ballot(match);
    if (wv < 2 && lane == 0) wmask[wv] = m;
    __syncthreads();
    if (match) {
      int pos = __popcll(wmask[wv] & ((1ull << lane) - 1ull));
      if (wv == 1) pos += __popcll(wmask[0]);
      alist[pos] = tid | (cb << 8);
    }
    __syncthreads();   // also drains all vmem: ledger starts at 0
  }
  const int cnt = __popcll(wmask[0]) + __popcll(wmask[1]);

  f32x4 acc[4][4];
  #pragma unroll
  for (int a = 0; a < 4; ++a)
    #pragma unroll
    for (int b = 0; b < 4; ++b) {
      f32x4 z = {0.f, 0.f, 0.f, 0.f};
      acc[a][b] = z;
    }

  const size_t srow0 = (size_t)n * SROWS + t0;  // S row of LDS row u=0
  const int lxb = tid * 16;                     // lane byte within a 4KB round

  auto issue_x = [&](int cb) {                  // 9 rounds = 36 KB, single buf
    #pragma unroll
    for (int q = 0; q < 9; ++q) {
      const int lb = q * 4096 + lxb;
      const int u  = lb >> 7;                   // LDS row (128 B rows)
      const int ib = (lb >> 1) & 63;
      GLL(S + (srow0 + u) * C_LEN + cb * 64 + ib, (char*)xst + lb);
    }
  };
  auto issue_w = [&](const bf16_t* wblk, int c, int buf) {  // 2 rounds = 8 KB
    const bf16_t* wsrc = wblk + (size_t)c * 4096;
    #pragma unroll
    for (int p = 0; p < 2; ++p) {
      const int lb = p * 4096 + lxb;
      GLL(wsrc + (lb >> 1), (char*)wlds[buf] + lb);
    }
  };

  if (cnt > 0) {
    issue_x(alist[0] >> 8);                             // x(0):9
    issue_w(wpk + (size_t)(alist[0] & 255) * 65536, 0, 0);  // W(0,0):2
  }

  for (int j = 0; j < cnt; ++j) {
    const bf16_t* wblk = wpk + (size_t)(alist[j] & 255) * 65536;
    const bool havenext = (j + 1 < cnt);
    const int anext = havenext ? alist[j + 1] : 0;

    #pragma unroll
    for (int c = 0; c < 16; ++c) {
      // ---- issues (program order = FIFO ledger) ----
      if (c < 15) {
        issue_w(wblk, c + 1, (c + 1) & 1);
      } else if (havenext) {
        issue_w(wpk + (size_t)(anext & 255) * 65536, 0, 0);  // next W0
      }

      // ---- counted wait (x + W(c) landed; W(c+1) stays in flight) ----
      if (c < 15 || havenext) {
        asm volatile("s_waitcnt vmcnt(2)" ::: "memory");
      } else {
        asm volatile("s_waitcnt vmcnt(0)" ::: "memory");
      }
      __builtin_amdgcn_s_barrier();       // B_ready(c)
      __builtin_amdgcn_sched_barrier(0);

      const bf16_t* wl = wlds[c & 1];
      __builtin_amdgcn_s_setprio(1);
      #pragma unroll
      for (int ksl = 0; ksl < 2; ++ksl) {
        const int k  = c;                     // conv tap (= ks>>1, ks=2c+ksl)
        const int ih = ksl * 32;              // channel half
        bf16x8 afr[4];
        #pragma unroll
        for (int mt = 0; mt < 4; ++mt)
          afr[mt] = *(const bf16x8*)(wl + ((ksl * 4 + mt) * 64 + lane) * 8);
        const int ub   = wv * 64 + (lane & 15) + k + 1;
        const int scol = (ih + ((lane >> 4) & 3) * 8) ^ ((ub & 7) << 3);
        bf16x8 bfr[4];
        #pragma unroll
        for (int nt = 0; nt < 4; ++nt)
          bfr[nt] = *(const bf16x8*)(xst + (ub + nt * 16) * 64 + scol);
        #pragma unroll
        for (int mt = 0; mt < 4; ++mt)
          #pragma unroll
          for (int nt = 0; nt < 4; ++nt)
            acc[mt][nt] = __builtin_amdgcn_mfma_f32_16x16x32_bf16(
                afr[mt], bfr[nt], acc[mt][nt], 0, 0, 0);
      }
      __builtin_amdgcn_s_setprio(0);
      __builtin_amdgcn_sched_barrier(0);
      __builtin_amdgcn_s_barrier();       // B_done(c): buffers reusable
    }

    // next block's x into the single buffer: all waves past c=15's trailing
    // barrier (xst reads lgkm-drained), so the DMA overwrite is safe.
    if (havenext) issue_x(anext >> 8);
  }

  // ---- store (each output element exactly once; empty rows store zeros) ----
  const int mlo = ((lane >> 4) & 3) * 4, nn = lane & 15;
  #pragma unroll
  for (int mt = 0; mt < 4; ++mt) {
    #pragma unroll
    for (int nt = 0; nt < 4; ++nt) {
      const int t = t0 + wv * 64 + nt * 16 + nn;
      float* yp = y + ((size_t)n * C_LEN + (size_t)(tr * 64 + mt * 16 + mlo)) * T_LEN + t;
      #pragma unroll
      for (int r = 0; r < 4; ++r)
        yp[(size_t)r * T_LEN] = acc[mt][nt][r];
    }
  }
}

extern "C" void kernel_launch(void* const* d_in, const int* in_sizes, int n_in,
                              void* d_out, int out_size, void* d_ws, size_t ws_size,
                              hipStream_t stream) {
  const float* x   = (const float*)d_in[0];
  const float* bv  = (const float*)d_in[1];
  const int* cols  = (const int*)d_in[2];
  const int* rows  = (const int*)d_in[3];
  float* y = (float*)d_out;

  // ws layout: [wpk: 16,777,216 B][S: 33,882,112 B]  (needs ws >= 50.7 MB)
  bf16_t* wpk = (bf16_t*)d_ws;
  bf16_t* S   = (bf16_t*)((char*)d_ws + 16777216);

  prepack_kernel<<<dim3(128, 4), dim3(256), 0, stream>>>(bv, wpk);
  padzero_kernel<<<dim3(80), dim3(256), 0, stream>>>(S);
  xprep_kernel<<<dim3(32, 32, 4), dim3(256), 0, stream>>>(x, S);
  bsconv_kernel<<<dim3(8, 32, 4), dim3(256), 0, stream>>>(S, wpk, cols, rows, y);
}